// Round 1
// baseline (12065.288 us; speedup 1.0000x reference)
//
#include <hip/hip_runtime.h>
#include <math.h>

// Problem constants (match reference)
#define B_    16
#define T_    256
#define D_    1024
#define H_    16
#define DH_   64
#define NB_   6
#define GD_   300
#define MLPH_ 2048
#define FFH_  4096
#define NTOK  (B_ * T_)            // 4096 token rows
#define NEGV  -4294967296.0f       // float32 rounding of -(2^32)+1

// ---------------------------------------------------------------------------
// Embedding gather: EMB[row, :] = emb_table[syb_ipt[row], :]
// ---------------------------------------------------------------------------
__global__ __launch_bounds__(256)
void gather_kernel(const int* __restrict__ ipt, const float* __restrict__ emb,
                   float* __restrict__ out)
{
    int row = blockIdx.x;                 // 0..4095
    int v = ipt[row];
    const float* src = emb + (size_t)v * GD_;
    float* dst = out + (size_t)row * GD_;
    for (int c = threadIdx.x; c < GD_; c += blockDim.x) dst[c] = src[c];
}

// ---------------------------------------------------------------------------
// Generic fp32 GEMM: C = act(A(MxK) @ B(KxN) + bias [+ pos broadcast])
// 64x64 tile, 256 threads, 4x4 micro-tile per thread, K-tile 16.
// M, N multiples of 64; K arbitrary (guarded).
// ---------------------------------------------------------------------------
template<bool RELU, bool ADDPOS>
__global__ __launch_bounds__(256)
void gemm_kernel(const float* __restrict__ A, const float* __restrict__ Bm,
                 const float* __restrict__ bias, const float* __restrict__ pos,
                 float* __restrict__ C, int M, int N, int K)
{
    __shared__ float As[16][64];
    __shared__ float Bs[16][64];
    const int tid = threadIdx.x;
    const int m0 = blockIdx.y * 64;
    const int n0 = blockIdx.x * 64;
    const int ty = tid >> 4;            // 0..15 -> C rows ty*4..ty*4+3
    const int tx = tid & 15;            // 0..15 -> C cols tx*4..tx*4+3
    const int alm = tid >> 2;           // A load: row in tile 0..63
    const int alk = (tid & 3) * 4;      // A load: k offset 0,4,8,12
    const int blkr = tid >> 4;          // B load: k row 0..15
    const int bln = (tid & 15) * 4;     // B load: n offset 0..60

    float acc[4][4];
#pragma unroll
    for (int i = 0; i < 4; i++)
#pragma unroll
        for (int j = 0; j < 4; j++) acc[i][j] = 0.f;

    for (int kt = 0; kt < K; kt += 16) {
        // stage A tile (64 x 16), transposed into As[k][m]
        {
            int k = kt + alk;
            const float* ap = A + (size_t)(m0 + alm) * K + k;
            float a0, a1, a2, a3;
            if (k + 3 < K) {
                float4 t = *(const float4*)ap;
                a0 = t.x; a1 = t.y; a2 = t.z; a3 = t.w;
            } else {
                a0 = (k + 0 < K) ? ap[0] : 0.f;
                a1 = (k + 1 < K) ? ap[1] : 0.f;
                a2 = (k + 2 < K) ? ap[2] : 0.f;
                a3 = (k + 3 < K) ? ap[3] : 0.f;
            }
            As[alk + 0][alm] = a0; As[alk + 1][alm] = a1;
            As[alk + 2][alm] = a2; As[alk + 3][alm] = a3;
        }
        // stage B tile (16 x 64)
        {
            int k = kt + blkr;
            float4 t = make_float4(0.f, 0.f, 0.f, 0.f);
            if (k < K) t = *(const float4*)(Bm + (size_t)k * N + n0 + bln);
            *(float4*)&Bs[blkr][bln] = t;
        }
        __syncthreads();
#pragma unroll
        for (int kk = 0; kk < 16; kk++) {
            float4 av = *(const float4*)&As[kk][ty * 4];
            float4 bv = *(const float4*)&Bs[kk][tx * 4];
            float a_[4] = {av.x, av.y, av.z, av.w};
            float b_[4] = {bv.x, bv.y, bv.z, bv.w};
#pragma unroll
            for (int i = 0; i < 4; i++)
#pragma unroll
                for (int j = 0; j < 4; j++) acc[i][j] += a_[i] * b_[j];
        }
        __syncthreads();
    }

    // epilogue
#pragma unroll
    for (int i = 0; i < 4; i++) {
        int row = m0 + ty * 4 + i;
        int col = n0 + tx * 4;
        float4 bb = *(const float4*)(bias + col);
        float4 v;
        v.x = acc[i][0] + bb.x; v.y = acc[i][1] + bb.y;
        v.z = acc[i][2] + bb.z; v.w = acc[i][3] + bb.w;
        if (ADDPOS) {
            float4 p = *(const float4*)(pos + (size_t)(row & (T_ - 1)) * N + col);
            v.x += p.x; v.y += p.y; v.z += p.z; v.w += p.w;
        }
        if (RELU) {
            v.x = fmaxf(v.x, 0.f); v.y = fmaxf(v.y, 0.f);
            v.z = fmaxf(v.z, 0.f); v.w = fmaxf(v.w, 0.f);
        }
        *(float4*)(C + (size_t)row * N + col) = v;
    }
}

// ---------------------------------------------------------------------------
// Attention: one wave (64 threads) per (b, h, q-row).
// s[k] = (q . k)/8, masked by key-pad mask and graph mask; softmax over k;
// o[d] = sum_k a[k] * V[b,k,h,d], scaled by qscale = syb_mask[b,q].
// ---------------------------------------------------------------------------
__global__ __launch_bounds__(64)
void attn_kernel(const float* __restrict__ Q, const float* __restrict__ K,
                 const float* __restrict__ V, const int* __restrict__ mask,
                 const int* __restrict__ graph, float* __restrict__ O)
{
    const int tid = threadIdx.x;
    const int bid = blockIdx.x;           // b*H*T + h*T + tq
    const int tq = bid & (T_ - 1);
    const int h  = (bid >> 8) & (H_ - 1);
    const int b  = bid >> 12;

    __shared__ float qs[DH_];
    __shared__ float as_[T_];

    const size_t qrow = ((size_t)(b * T_ + tq)) * D_ + h * DH_;
    qs[tid] = Q[qrow + tid];
    __syncthreads();

    float s[4];
#pragma unroll
    for (int j = 0; j < 4; j++) {
        int k = tid + j * 64;
        const float* krow = K + ((size_t)(b * T_ + k)) * D_ + h * DH_;
        float dot = 0.f;
#pragma unroll
        for (int d = 0; d < DH_; d += 4) {
            float4 kv = *(const float4*)(krow + d);
            dot += qs[d] * kv.x + qs[d + 1] * kv.y + qs[d + 2] * kv.z + qs[d + 3] * kv.w;
        }
        float sv = dot * 0.125f;   // 1/sqrt(64)
        if (mask[b * T_ + k] == 0 || graph[((size_t)(b * T_ + tq)) * T_ + k] == 0)
            sv = NEGV;
        s[j] = sv;
    }

    // wave softmax over 256 scores (4 per lane)
    float m = fmaxf(fmaxf(s[0], s[1]), fmaxf(s[2], s[3]));
#pragma unroll
    for (int off = 32; off > 0; off >>= 1) m = fmaxf(m, __shfl_xor(m, off, 64));
    float e[4];
    float lsum = 0.f;
#pragma unroll
    for (int j = 0; j < 4; j++) { e[j] = expf(s[j] - m); lsum += e[j]; }
#pragma unroll
    for (int off = 32; off > 0; off >>= 1) lsum += __shfl_xor(lsum, off, 64);
    float inv = 1.f / lsum;
#pragma unroll
    for (int j = 0; j < 4; j++) as_[tid + j * 64] = e[j] * inv;
    __syncthreads();

    // o[d], d = tid; V reads coalesced across lanes
    const float qsc = (float)mask[b * T_ + tq];
    const float* vbase = V + ((size_t)(b * T_)) * D_ + h * DH_ + tid;
    float acc = 0.f;
#pragma unroll 4
    for (int k = 0; k < T_; k++) acc += as_[k] * vbase[(size_t)k * D_];
    O[qrow + tid] = acc * qsc;
}

// ---------------------------------------------------------------------------
// Residual add + LayerNorm (two-pass, matches jnp mean/var numerics, eps=1e-8)
// Out[row,:] = ( (X+Y) - mean ) / sqrt(var + 1e-8) * g + beta
// In-place safe (reads into regs before any write).
// ---------------------------------------------------------------------------
__global__ __launch_bounds__(256)
void add_ln_kernel(const float* __restrict__ Xin, const float* __restrict__ Yin,
                   const float* __restrict__ g, const float* __restrict__ beta,
                   float* __restrict__ Out)
{
    const int row = blockIdx.x;
    const int tid = threadIdx.x;
    const float4 a = ((const float4*)(Xin + (size_t)row * D_))[tid];
    const float4 b = ((const float4*)(Yin + (size_t)row * D_))[tid];
    float v0 = a.x + b.x, v1 = a.y + b.y, v2 = a.z + b.z, v3 = a.w + b.w;

    __shared__ float red[8];
    float lsum = v0 + v1 + v2 + v3;
#pragma unroll
    for (int off = 32; off > 0; off >>= 1) lsum += __shfl_xor(lsum, off, 64);
    int wave = tid >> 6;
    if ((tid & 63) == 0) red[wave] = lsum;
    __syncthreads();
    float mean = (red[0] + red[1] + red[2] + red[3]) * (1.f / (float)D_);

    float d0 = v0 - mean, d1 = v1 - mean, d2 = v2 - mean, d3 = v3 - mean;
    float ls2 = d0 * d0 + d1 * d1 + d2 * d2 + d3 * d3;
#pragma unroll
    for (int off = 32; off > 0; off >>= 1) ls2 += __shfl_xor(ls2, off, 64);
    if ((tid & 63) == 0) red[4 + wave] = ls2;
    __syncthreads();
    float var = (red[4] + red[5] + red[6] + red[7]) * (1.f / (float)D_);
    float inv = 1.f / sqrtf(var + 1e-8f);

    int col = tid * 4;
    float4 gv = *(const float4*)(g + col);
    float4 bv = *(const float4*)(beta + col);
    float4 o;
    o.x = d0 * inv * gv.x + bv.x;
    o.y = d1 * inv * gv.y + bv.y;
    o.z = d2 * inv * gv.z + bv.z;
    o.w = d3 * inv * gv.w + bv.w;
    ((float4*)(Out + (size_t)row * D_))[tid] = o;
}

// ---------------------------------------------------------------------------
extern "C" void kernel_launch(void* const* d_in, const int* in_sizes, int n_in,
                              void* d_out, int out_size, void* d_ws, size_t ws_size,
                              hipStream_t stream)
{
    const int*   syb_ipt   = (const int*)d_in[0];
    const int*   syb_mask  = (const int*)d_in[1];
    const int*   syb_graph = (const int*)d_in[2];
    const float* emb       = (const float*)d_in[3];
    const float* mlp_w1    = (const float*)d_in[4];
    const float* mlp_b1    = (const float*)d_in[5];
    const float* mlp_w2    = (const float*)d_in[6];
    const float* mlp_b2    = (const float*)d_in[7];
    const float* pos       = (const float*)d_in[8];
    const float* wq        = (const float*)d_in[9];
    const float* bq        = (const float*)d_in[10];
    const float* wk        = (const float*)d_in[11];
    const float* bk        = (const float*)d_in[12];
    const float* wv        = (const float*)d_in[13];
    const float* bv        = (const float*)d_in[14];
    const float* ln1g      = (const float*)d_in[15];
    const float* ln1b      = (const float*)d_in[16];
    const float* ffw1      = (const float*)d_in[17];
    const float* ffb1      = (const float*)d_in[18];
    const float* ffw2      = (const float*)d_in[19];
    const float* ffb2      = (const float*)d_in[20];
    const float* ln2g      = (const float*)d_in[21];
    const float* ln2b      = (const float*)d_in[22];

    // workspace layout (floats); total ~43.2M floats ~ 173 MB
    float* ws   = (float*)d_ws;
    float* X    = ws;                        // 4096*1024
    float* EMB  = X    + (size_t)NTOK * D_;  // 4096*300
    float* HBUF = EMB  + (size_t)NTOK * GD_; // 4096*4096 (MLP hidden & FF hidden)
    float* Qb   = HBUF + (size_t)NTOK * FFH_;
    float* Kb   = Qb   + (size_t)NTOK * D_;
    float* Vb   = Kb   + (size_t)NTOK * D_;
    float* Ob   = Vb   + (size_t)NTOK * D_;
    float* Fb   = Ob   + (size_t)NTOK * D_;

    dim3 blk(256);

    // 1) gather embeddings
    gather_kernel<<<NTOK, 256, 0, stream>>>(syb_ipt, emb, EMB);

    // 2) MLP layer 1: relu(EMB @ w1 + b1) -> HBUF (4096 x 2048)
    gemm_kernel<true, false><<<dim3(MLPH_ / 64, NTOK / 64), blk, 0, stream>>>(
        EMB, mlp_w1, mlp_b1, nullptr, HBUF, NTOK, MLPH_, GD_);

    // 3) MLP layer 2 + positional add: HBUF @ w2 + b2 + pos -> X (4096 x 1024)
    gemm_kernel<false, true><<<dim3(D_ / 64, NTOK / 64), blk, 0, stream>>>(
        HBUF, mlp_w2, mlp_b2, pos, X, NTOK, D_, MLPH_);

    for (int i = 0; i < NB_; i++) {
        const float* wq_i = wq + (size_t)i * D_ * D_;
        const float* wk_i = wk + (size_t)i * D_ * D_;
        const float* wv_i = wv + (size_t)i * D_ * D_;

        // QKV projections with relu
        gemm_kernel<true, false><<<dim3(D_ / 64, NTOK / 64), blk, 0, stream>>>(
            X, wq_i, bq + (size_t)i * D_, nullptr, Qb, NTOK, D_, D_);
        gemm_kernel<true, false><<<dim3(D_ / 64, NTOK / 64), blk, 0, stream>>>(
            X, wk_i, bk + (size_t)i * D_, nullptr, Kb, NTOK, D_, D_);
        gemm_kernel<true, false><<<dim3(D_ / 64, NTOK / 64), blk, 0, stream>>>(
            X, wv_i, bv + (size_t)i * D_, nullptr, Vb, NTOK, D_, D_);

        // attention
        attn_kernel<<<B_ * H_ * T_, 64, 0, stream>>>(Qb, Kb, Vb, syb_mask, syb_graph, Ob);

        // x = LN(o + x)
        add_ln_kernel<<<NTOK, 256, 0, stream>>>(
            X, Ob, ln1g + (size_t)i * D_, ln1b + (size_t)i * D_, X);

        // FF: relu(x @ ff_w1 + b1) -> HBUF (4096 x 4096)
        gemm_kernel<true, false><<<dim3(FFH_ / 64, NTOK / 64), blk, 0, stream>>>(
            X, ffw1 + (size_t)i * D_ * FFH_, ffb1 + (size_t)i * FFH_, nullptr,
            HBUF, NTOK, FFH_, D_);
        // HBUF @ ff_w2 + b2 -> Fb (4096 x 1024)
        gemm_kernel<false, false><<<dim3(D_ / 64, NTOK / 64), blk, 0, stream>>>(
            HBUF, ffw2 + (size_t)i * FFH_ * D_, ffb2 + (size_t)i * D_, nullptr,
            Fb, NTOK, D_, FFH_);

        // x = LN(h + x); last block writes straight to d_out
        float* out_ptr = (i == NB_ - 1) ? (float*)d_out : X;
        add_ln_kernel<<<NTOK, 256, 0, stream>>>(
            X, Fb, ln2g + (size_t)i * D_, ln2b + (size_t)i * D_, out_ptr);
    }
}

// Round 2
// 4383.472 us; speedup vs baseline: 2.7525x; 2.7525x over previous
//
#include <hip/hip_runtime.h>
#include <hip/hip_bf16.h>
#include <math.h>

#define B_    16
#define T_    256
#define D_    1024
#define H_    16
#define DH_   64
#define NB_   6
#define GD_   300
#define GDP_  320            // padded K for MLP1
#define MLPH_ 2048
#define FFH_  4096
#define NTOK  (B_ * T_)
#define NEGV  -4294967296.0f

typedef __hip_bfloat16 bf16;
typedef __attribute__((ext_vector_type(8))) short short8;
typedef __attribute__((ext_vector_type(4))) float floatx4;

__device__ __forceinline__ float blo(unsigned u) { union { unsigned i; float f; } x; x.i = u << 16; return x.f; }
__device__ __forceinline__ float bhi(unsigned u) { union { unsigned i; float f; } x; x.i = u & 0xffff0000u; return x.f; }
__device__ __forceinline__ unsigned short f2b(float v) {
    __hip_bfloat16 h = __float2bfloat16(v);
    return __builtin_bit_cast(unsigned short, h);
}

// async 16B global -> LDS (lds dest = wave-uniform base + lane*16)
__device__ __forceinline__ void gld16(const void* g, void* l) {
    __builtin_amdgcn_global_load_lds(
        (const __attribute__((address_space(1))) unsigned int*)g,
        (__attribute__((address_space(3))) unsigned int*)(uintptr_t)l,
        16, 0, 0);
}

// ---------------------------------------------------------------------------
// fp32 -> bf16 transpose: W (K x N, row-major) -> WT (N x Kpad, row-major).
// Rows k >= K are zero-filled. grid = (N/32, Kpad/32, batch), 256 threads.
// ---------------------------------------------------------------------------
__global__ __launch_bounds__(256)
void convT_kernel(const float* __restrict__ W, bf16* __restrict__ WT,
                  int K, int N, int Kpad, size_t strideIn, size_t strideOut)
{
    __shared__ float t[32][33];
    const float* Wb = W + (size_t)blockIdx.z * strideIn;
    bf16* WTb = WT + (size_t)blockIdx.z * strideOut;
    int n0 = blockIdx.x * 32, k0 = blockIdx.y * 32;
    int tx = threadIdx.x & 31, ty = threadIdx.x >> 5;   // ty 0..7
#pragma unroll
    for (int r = 0; r < 4; r++) {
        int k = k0 + ty + r * 8;
        t[ty + r * 8][tx] = (k < K) ? Wb[(size_t)k * N + n0 + tx] : 0.f;
    }
    __syncthreads();
#pragma unroll
    for (int r = 0; r < 4; r++) {
        int n = n0 + ty + r * 8;
        WTb[(size_t)n * Kpad + k0 + tx] = __float2bfloat16(t[tx][ty + r * 8]);
    }
}

// ---------------------------------------------------------------------------
// Embedding gather -> bf16, K padded 300->320 with zeros
// ---------------------------------------------------------------------------
__global__ __launch_bounds__(256)
void gather_kernel(const int* __restrict__ ipt, const float* __restrict__ emb,
                   bf16* __restrict__ out)
{
    int row = blockIdx.x;
    int v = ipt[row];
    const float* src = emb + (size_t)v * GD_;
    bf16* dst = out + (size_t)row * GDP_;
    for (int c = threadIdx.x; c < GDP_; c += blockDim.x)
        dst[c] = (c < GD_) ? __float2bfloat16(src[c]) : __float2bfloat16(0.f);
}

// ---------------------------------------------------------------------------
// bf16 MFMA GEMM: C = act(A @ B + bias [+pos]), A: MxK bf16 row-major,
// BT: NxK bf16 row-major (B transposed). 128x128 tile, BK=64, 256 threads,
// 4 waves each 64x64 via 4x4 grid of 16x16x32 MFMAs. fp32 accumulate.
// XOR-swizzled LDS chunks: chunk(row,kc) stored at row*8 + (kc ^ (row&7)).
// Staged via global_load_lds width=16. M%128==0, N%128==0, K%64==0 required.
// ---------------------------------------------------------------------------
template<bool RELU, bool ADDPOS, bool DUAL, typename OutT>
__global__ __launch_bounds__(256)
void mm_bf16(const bf16* __restrict__ A, const bf16* __restrict__ BT,
             const float* __restrict__ bias, const float* __restrict__ pos,
             OutT* __restrict__ C, bf16* __restrict__ C2,
             int M, int N, int K)
{
    __shared__ __align__(16) short lsA[8192];   // 128 rows x 8 chunks x 8 bf16
    __shared__ __align__(16) short lsB[8192];
    const int tid = threadIdx.x;
    const int wv = tid >> 6, ln = tid & 63;
    const int m0 = blockIdx.y * 128, n0 = blockIdx.x * 128;
    const int wm = (wv >> 1) * 64, wn = (wv & 1) * 64;
    const int ml = ln & 15, q = ln >> 4;

    floatx4 acc[4][4] = {};

    // staging assignment: chunk c = (p*4+wv)*64 + ln; row = c>>3, kc = (c&7)^(row&7)
    const int cbase[4] = { (0 * 4 + wv) * 64, (1 * 4 + wv) * 64, (2 * 4 + wv) * 64, (3 * 4 + wv) * 64 };
    int srow[4], skc[4];
#pragma unroll
    for (int p = 0; p < 4; p++) {
        int c = cbase[p] + ln;
        srow[p] = c >> 3;
        skc[p] = (c & 7) ^ (srow[p] & 7);
    }

    for (int kt = 0; kt < K; kt += 64) {
#pragma unroll
        for (int p = 0; p < 4; p++) {
            const bf16* ga = A + (size_t)(m0 + srow[p]) * K + kt + skc[p] * 8;
            const bf16* gb = BT + (size_t)(n0 + srow[p]) * K + kt + skc[p] * 8;
            gld16(ga, &lsA[cbase[p] * 8]);
            gld16(gb, &lsB[cbase[p] * 8]);
        }
        __syncthreads();

        short8 af[4][2], bfr[4][2];
#pragma unroll
        for (int i = 0; i < 4; i++) {
#pragma unroll
            for (int ks = 0; ks < 2; ks++) {
                int r = wm + i * 16 + ml;
                int kc = ks * 4 + q;
                af[i][ks] = *(const short8*)&lsA[(r * 8 + (kc ^ (r & 7))) * 8];
                int n = wn + i * 16 + ml;
                bfr[i][ks] = *(const short8*)&lsB[(n * 8 + (kc ^ (n & 7))) * 8];
            }
        }
#pragma unroll
        for (int ks = 0; ks < 2; ks++)
#pragma unroll
            for (int i = 0; i < 4; i++)
#pragma unroll
                for (int j = 0; j < 4; j++)
                    acc[i][j] = __builtin_amdgcn_mfma_f32_16x16x32_bf16(
                        af[i][ks], bfr[j][ks], acc[i][j], 0, 0, 0);
        __syncthreads();
    }

    // epilogue: C/D layout col = lane&15, row = (lane>>4)*4 + reg
#pragma unroll
    for (int i = 0; i < 4; i++) {
#pragma unroll
        for (int j = 0; j < 4; j++) {
            int col = n0 + wn + j * 16 + ml;
            float bb = bias[col];
#pragma unroll
            for (int rg = 0; rg < 4; rg++) {
                int row = m0 + wm + i * 16 + q * 4 + rg;
                float v = acc[i][j][rg] + bb;
                if (ADDPOS) v += pos[(size_t)(row & (T_ - 1)) * N + col];
                if (RELU) v = fmaxf(v, 0.f);
                size_t idx = (size_t)row * N + col;
                if constexpr (sizeof(OutT) == 4) C[idx] = v;
                else C[idx] = (OutT)__float2bfloat16(v);
                if (DUAL) C2[idx] = __float2bfloat16(v);
            }
        }
    }
}

// ---------------------------------------------------------------------------
// Attention: one wave per (b, h, q-row). Q/K/V bf16, output fp32.
// ---------------------------------------------------------------------------
__global__ __launch_bounds__(64)
void attn_kernel(const bf16* __restrict__ Q, const bf16* __restrict__ Km,
                 const bf16* __restrict__ Vm, const int* __restrict__ mask,
                 const int* __restrict__ graph, float* __restrict__ O)
{
    const int tid = threadIdx.x;
    const int bid = blockIdx.x;
    const int tq = bid & (T_ - 1);
    const int h  = (bid >> 8) & (H_ - 1);
    const int b  = bid >> 12;

    __shared__ float qs[DH_];
    __shared__ float as_[T_];

    const size_t qrow = ((size_t)(b * T_ + tq)) * D_ + h * DH_;
    qs[tid] = __bfloat162float(Q[qrow + tid]);
    __syncthreads();

    float s[4];
#pragma unroll
    for (int j = 0; j < 4; j++) {
        int k = tid + j * 64;
        const bf16* krow = Km + ((size_t)(b * T_ + k)) * D_ + h * DH_;
        float dot = 0.f;
#pragma unroll
        for (int d = 0; d < DH_; d += 8) {
            uint4 u = *(const uint4*)&krow[d];
            dot += qs[d + 0] * blo(u.x) + qs[d + 1] * bhi(u.x);
            dot += qs[d + 2] * blo(u.y) + qs[d + 3] * bhi(u.y);
            dot += qs[d + 4] * blo(u.z) + qs[d + 5] * bhi(u.z);
            dot += qs[d + 6] * blo(u.w) + qs[d + 7] * bhi(u.w);
        }
        float sv = dot * 0.125f;
        if (mask[b * T_ + k] == 0 || graph[((size_t)(b * T_ + tq)) * T_ + k] == 0)
            sv = NEGV;
        s[j] = sv;
    }

    float m = fmaxf(fmaxf(s[0], s[1]), fmaxf(s[2], s[3]));
#pragma unroll
    for (int off = 32; off > 0; off >>= 1) m = fmaxf(m, __shfl_xor(m, off, 64));
    float e[4];
    float lsum = 0.f;
#pragma unroll
    for (int j = 0; j < 4; j++) { e[j] = expf(s[j] - m); lsum += e[j]; }
#pragma unroll
    for (int off = 32; off > 0; off >>= 1) lsum += __shfl_xor(lsum, off, 64);
    float inv = 1.f / lsum;
#pragma unroll
    for (int j = 0; j < 4; j++) as_[tid + j * 64] = e[j] * inv;
    __syncthreads();

    const float qsc = (float)mask[b * T_ + tq];
    const bf16* vbase = Vm + ((size_t)(b * T_)) * D_ + h * DH_ + tid;
    float acc = 0.f;
#pragma unroll 4
    for (int k = 0; k < T_; k++)
        acc += as_[k] * __bfloat162float(vbase[(size_t)k * D_]);
    O[qrow + tid] = acc * qsc;
}

// ---------------------------------------------------------------------------
// Residual add + LayerNorm, fp32; also writes bf16 copy for next GEMM input.
// ---------------------------------------------------------------------------
__global__ __launch_bounds__(256)
void add_ln_kernel(const float* __restrict__ Xin, const float* __restrict__ Yin,
                   const float* __restrict__ g, const float* __restrict__ beta,
                   float* __restrict__ Out, bf16* __restrict__ Outb)
{
    const int row = blockIdx.x;
    const int tid = threadIdx.x;
    const float4 a = ((const float4*)(Xin + (size_t)row * D_))[tid];
    const float4 b = ((const float4*)(Yin + (size_t)row * D_))[tid];
    float v0 = a.x + b.x, v1 = a.y + b.y, v2 = a.z + b.z, v3 = a.w + b.w;

    __shared__ float red[8];
    float lsum = v0 + v1 + v2 + v3;
#pragma unroll
    for (int off = 32; off > 0; off >>= 1) lsum += __shfl_xor(lsum, off, 64);
    int wave = tid >> 6;
    if ((tid & 63) == 0) red[wave] = lsum;
    __syncthreads();
    float mean = (red[0] + red[1] + red[2] + red[3]) * (1.f / (float)D_);

    float d0 = v0 - mean, d1 = v1 - mean, d2 = v2 - mean, d3 = v3 - mean;
    float ls2 = d0 * d0 + d1 * d1 + d2 * d2 + d3 * d3;
#pragma unroll
    for (int off = 32; off > 0; off >>= 1) ls2 += __shfl_xor(ls2, off, 64);
    if ((tid & 63) == 0) red[4 + wave] = ls2;
    __syncthreads();
    float var = (red[4] + red[5] + red[6] + red[7]) * (1.f / (float)D_);
    float inv = 1.f / sqrtf(var + 1e-8f);

    int col = tid * 4;
    float4 gv = *(const float4*)(g + col);
    float4 bv = *(const float4*)(beta + col);
    float4 o;
    o.x = d0 * inv * gv.x + bv.x;
    o.y = d1 * inv * gv.y + bv.y;
    o.z = d2 * inv * gv.z + bv.z;
    o.w = d3 * inv * gv.w + bv.w;
    ((float4*)(Out + (size_t)row * D_))[tid] = o;

    union { unsigned short u[4]; uint2 v; } pk;
    pk.u[0] = f2b(o.x); pk.u[1] = f2b(o.y); pk.u[2] = f2b(o.z); pk.u[3] = f2b(o.w);
    *(uint2*)&Outb[(size_t)row * D_ + col] = pk.v;
}

// ---------------------------------------------------------------------------
extern "C" void kernel_launch(void* const* d_in, const int* in_sizes, int n_in,
                              void* d_out, int out_size, void* d_ws, size_t ws_size,
                              hipStream_t stream)
{
    const int*   syb_ipt   = (const int*)d_in[0];
    const int*   syb_mask  = (const int*)d_in[1];
    const int*   syb_graph = (const int*)d_in[2];
    const float* emb       = (const float*)d_in[3];
    const float* mlp_w1    = (const float*)d_in[4];
    const float* mlp_b1    = (const float*)d_in[5];
    const float* mlp_w2    = (const float*)d_in[6];
    const float* mlp_b2    = (const float*)d_in[7];
    const float* pos       = (const float*)d_in[8];
    const float* wq        = (const float*)d_in[9];
    const float* bq        = (const float*)d_in[10];
    const float* wk        = (const float*)d_in[11];
    const float* bk        = (const float*)d_in[12];
    const float* wv        = (const float*)d_in[13];
    const float* bv        = (const float*)d_in[14];
    const float* ln1g      = (const float*)d_in[15];
    const float* ln1b      = (const float*)d_in[16];
    const float* ffw1      = (const float*)d_in[17];
    const float* ffb1      = (const float*)d_in[18];
    const float* ffw2      = (const float*)d_in[19];
    const float* ffb2      = (const float*)d_in[20];
    const float* ln2g      = (const float*)d_in[21];
    const float* ln2b      = (const float*)d_in[22];

    // workspace layout
    char* p = (char*)d_ws;
    auto alloc = [&](size_t bytes) { char* r = p; p += (bytes + 255) & ~(size_t)255; return r; };
    float* X    = (float*)alloc((size_t)NTOK * D_ * 4);       // fp32 residual
    float* Rb   = (float*)alloc((size_t)NTOK * D_ * 4);       // attn-out / ff2-out fp32
    bf16*  Xb   = (bf16*)alloc((size_t)NTOK * D_ * 2);        // bf16 copy of X
    bf16*  EMBb = (bf16*)alloc((size_t)NTOK * GDP_ * 2);
    bf16*  Hb   = (bf16*)alloc((size_t)NTOK * FFH_ * 2);      // MLP/FF hidden bf16
    bf16*  Qb   = (bf16*)alloc((size_t)NTOK * D_ * 2);
    bf16*  Kb   = (bf16*)alloc((size_t)NTOK * D_ * 2);
    bf16*  Vb   = (bf16*)alloc((size_t)NTOK * D_ * 2);
    bf16*  wqT  = (bf16*)alloc((size_t)NB_ * D_ * D_ * 2);
    bf16*  wkT  = (bf16*)alloc((size_t)NB_ * D_ * D_ * 2);
    bf16*  wvT  = (bf16*)alloc((size_t)NB_ * D_ * D_ * 2);
    bf16*  f1T  = (bf16*)alloc((size_t)NB_ * D_ * FFH_ * 2);
    bf16*  f2T  = (bf16*)alloc((size_t)NB_ * D_ * FFH_ * 2);
    bf16*  m1T  = (bf16*)alloc((size_t)MLPH_ * GDP_ * 2);
    bf16*  m2T  = (bf16*)alloc((size_t)D_ * MLPH_ * 2);

    // 0) weight convert + transpose (bf16, N x K)
    convT_kernel<<<dim3(D_ / 32, D_ / 32, NB_), 256, 0, stream>>>(
        wq, wqT, D_, D_, D_, (size_t)D_ * D_, (size_t)D_ * D_);
    convT_kernel<<<dim3(D_ / 32, D_ / 32, NB_), 256, 0, stream>>>(
        wk, wkT, D_, D_, D_, (size_t)D_ * D_, (size_t)D_ * D_);
    convT_kernel<<<dim3(D_ / 32, D_ / 32, NB_), 256, 0, stream>>>(
        wv, wvT, D_, D_, D_, (size_t)D_ * D_, (size_t)D_ * D_);
    convT_kernel<<<dim3(FFH_ / 32, D_ / 32, NB_), 256, 0, stream>>>(
        ffw1, f1T, D_, FFH_, D_, (size_t)D_ * FFH_, (size_t)D_ * FFH_);
    convT_kernel<<<dim3(D_ / 32, FFH_ / 32, NB_), 256, 0, stream>>>(
        ffw2, f2T, FFH_, D_, FFH_, (size_t)D_ * FFH_, (size_t)D_ * FFH_);
    convT_kernel<<<dim3(MLPH_ / 32, GDP_ / 32, 1), 256, 0, stream>>>(
        mlp_w1, m1T, GD_, MLPH_, GDP_, 0, 0);
    convT_kernel<<<dim3(D_ / 32, MLPH_ / 32, 1), 256, 0, stream>>>(
        mlp_w2, m2T, MLPH_, D_, MLPH_, 0, 0);

    // 1) gather embeddings (bf16, padded)
    gather_kernel<<<NTOK, 256, 0, stream>>>(syb_ipt, emb, EMBb);

    // 2) MLP1: relu(EMB @ w1 + b1) -> Hb (4096 x 2048)
    mm_bf16<true, false, false, bf16><<<dim3(MLPH_ / 128, NTOK / 128), 256, 0, stream>>>(
        EMBb, m1T, mlp_b1, nullptr, Hb, nullptr, NTOK, MLPH_, GDP_);
    // 3) MLP2 + pos -> X (fp32) + Xb (bf16)
    mm_bf16<false, true, true, float><<<dim3(D_ / 128, NTOK / 128), 256, 0, stream>>>(
        Hb, m2T, mlp_b2, pos, X, Xb, NTOK, D_, MLPH_);

    for (int i = 0; i < NB_; i++) {
        mm_bf16<true, false, false, bf16><<<dim3(D_ / 128, NTOK / 128), 256, 0, stream>>>(
            Xb, wqT + (size_t)i * D_ * D_, bq + (size_t)i * D_, nullptr, Qb, nullptr, NTOK, D_, D_);
        mm_bf16<true, false, false, bf16><<<dim3(D_ / 128, NTOK / 128), 256, 0, stream>>>(
            Xb, wkT + (size_t)i * D_ * D_, bk + (size_t)i * D_, nullptr, Kb, nullptr, NTOK, D_, D_);
        mm_bf16<true, false, false, bf16><<<dim3(D_ / 128, NTOK / 128), 256, 0, stream>>>(
            Xb, wvT + (size_t)i * D_ * D_, bv + (size_t)i * D_, nullptr, Vb, nullptr, NTOK, D_, D_);

        attn_kernel<<<B_ * H_ * T_, 64, 0, stream>>>(Qb, Kb, Vb, syb_mask, syb_graph, Rb);

        add_ln_kernel<<<NTOK, 256, 0, stream>>>(
            X, Rb, ln1g + (size_t)i * D_, ln1b + (size_t)i * D_, X, Xb);

        mm_bf16<true, false, false, bf16><<<dim3(FFH_ / 128, NTOK / 128), 256, 0, stream>>>(
            Xb, f1T + (size_t)i * D_ * FFH_, ffb1 + (size_t)i * FFH_, nullptr, Hb, nullptr, NTOK, FFH_, D_);
        mm_bf16<false, false, false, float><<<dim3(D_ / 128, NTOK / 128), 256, 0, stream>>>(
            Hb, f2T + (size_t)i * D_ * FFH_, ffb2 + (size_t)i * D_, nullptr, Rb, nullptr, NTOK, D_, FFH_);

        float* out_ptr = (i == NB_ - 1) ? (float*)d_out : X;
        add_ln_kernel<<<NTOK, 256, 0, stream>>>(
            X, Rb, ln2g + (size_t)i * D_, ln2b + (size_t)i * D_, out_ptr, Xb);
    }
}

// Round 3
// 2272.792 us; speedup vs baseline: 5.3086x; 1.9287x over previous
//
#include <hip/hip_runtime.h>
#include <hip/hip_bf16.h>
#include <math.h>

#define B_    16
#define T_    256
#define D_    1024
#define H_    16
#define DH_   64
#define NB_   6
#define GD_   300
#define GDP_  320
#define MLPH_ 2048
#define FFH_  4096
#define NTOK  (B_ * T_)
#define NEGV  -4294967296.0f

typedef __hip_bfloat16 bf16;
typedef __attribute__((ext_vector_type(8))) short short8;
typedef __attribute__((ext_vector_type(4))) float floatx4;

__device__ __forceinline__ unsigned short f2b(float v) {
    __hip_bfloat16 h = __float2bfloat16(v);
    return __builtin_bit_cast(unsigned short, h);
}
__device__ __forceinline__ float b2f(unsigned short u) {
    union { unsigned i; float f; } x; x.i = ((unsigned)u) << 16; return x.f;
}

// async 16B global -> LDS
__device__ __forceinline__ void gld16(const void* g, void* l) {
    __builtin_amdgcn_global_load_lds(
        (const __attribute__((address_space(1))) unsigned int*)g,
        (__attribute__((address_space(3))) unsigned int*)(uintptr_t)l,
        16, 0, 0);
}

// ---------------------------------------------------------------------------
// fp32 -> bf16 transpose: W (K x N) -> WT (N x Kpad). k >= K zero-filled.
// ---------------------------------------------------------------------------
__global__ __launch_bounds__(256)
void convT_kernel(const float* __restrict__ W, bf16* __restrict__ WT,
                  int K, int N, int Kpad, size_t strideIn, size_t strideOut)
{
    __shared__ float t[32][33];
    const float* Wb = W + (size_t)blockIdx.z * strideIn;
    bf16* WTb = WT + (size_t)blockIdx.z * strideOut;
    int n0 = blockIdx.x * 32, k0 = blockIdx.y * 32;
    int tx = threadIdx.x & 31, ty = threadIdx.x >> 5;
#pragma unroll
    for (int r = 0; r < 4; r++) {
        int k = k0 + ty + r * 8;
        t[ty + r * 8][tx] = (k < K) ? Wb[(size_t)k * N + n0 + tx] : 0.f;
    }
    __syncthreads();
#pragma unroll
    for (int r = 0; r < 4; r++) {
        int n = n0 + ty + r * 8;
        WTb[(size_t)n * Kpad + k0 + tx] = __float2bfloat16(t[tx][ty + r * 8]);
    }
}

// ---------------------------------------------------------------------------
// Embedding gather -> bf16, padded 300->320
// ---------------------------------------------------------------------------
__global__ __launch_bounds__(256)
void gather_kernel(const int* __restrict__ ipt, const float* __restrict__ emb,
                   bf16* __restrict__ out)
{
    int row = blockIdx.x;
    int v = ipt[row];
    const float* src = emb + (size_t)v * GD_;
    bf16* dst = out + (size_t)row * GDP_;
    for (int c = threadIdx.x; c < GDP_; c += blockDim.x)
        dst[c] = (c < GD_) ? __float2bfloat16(src[c]) : __float2bfloat16(0.f);
}

// ---------------------------------------------------------------------------
// graph/key-mask -> additive bias (0 or NEGV), bf16. grid = B*T blocks.
// ---------------------------------------------------------------------------
__global__ __launch_bounds__(256)
void gbias_kernel(const int* __restrict__ mask, const int* __restrict__ graph,
                  bf16* __restrict__ gb)
{
    int r = blockIdx.x;              // b*T + q
    int b = r >> 8;
    int k = threadIdx.x;
    int ok = mask[b * T_ + k] & graph[(size_t)r * T_ + k];
    gb[(size_t)r * T_ + k] = __float2bfloat16(ok ? 0.f : NEGV);
}

// concat per-layer q/k/v biases -> (NB, 3072)
__global__ __launch_bounds__(256)
void bcat_kernel(const float* __restrict__ bq, const float* __restrict__ bk,
                 const float* __restrict__ bv, float* __restrict__ out)
{
    int i = blockIdx.x;
    int j = blockIdx.y * 256 + threadIdx.x;   // 0..3071
    float v = (j < 1024) ? bq[i * 1024 + j]
            : (j < 2048) ? bk[i * 1024 + j - 1024]
                         : bv[i * 1024 + j - 2048];
    out[i * 3072 + j] = v;
}

// ---------------------------------------------------------------------------
// bf16 MFMA GEMM (m97 structure): 128x128 tile, BK=64, 4 waves.
// QKVQ: multiply cols < 1024 by 0.125 (fold attention scale into Q).
// ---------------------------------------------------------------------------
template<bool RELU, bool ADDPOS, bool DUAL, bool QKVQ, typename OutT>
__global__ __launch_bounds__(256)
void mm_bf16(const bf16* __restrict__ A, const bf16* __restrict__ BT,
             const float* __restrict__ bias, const float* __restrict__ pos,
             OutT* __restrict__ C, bf16* __restrict__ C2,
             int M, int N, int K)
{
    __shared__ __align__(16) short lsA[8192];
    __shared__ __align__(16) short lsB[8192];
    const int tid = threadIdx.x;
    const int wv = tid >> 6, ln = tid & 63;
    const int m0 = blockIdx.y * 128, n0 = blockIdx.x * 128;
    const int wm = (wv >> 1) * 64, wn = (wv & 1) * 64;
    const int ml = ln & 15, q = ln >> 4;

    floatx4 acc[4][4] = {};

    const int cbase[4] = { (0 * 4 + wv) * 64, (1 * 4 + wv) * 64, (2 * 4 + wv) * 64, (3 * 4 + wv) * 64 };
    int srow[4], skc[4];
#pragma unroll
    for (int p = 0; p < 4; p++) {
        int c = cbase[p] + ln;
        srow[p] = c >> 3;
        skc[p] = (c & 7) ^ (srow[p] & 7);
    }

    for (int kt = 0; kt < K; kt += 64) {
#pragma unroll
        for (int p = 0; p < 4; p++) {
            const bf16* ga = A + (size_t)(m0 + srow[p]) * K + kt + skc[p] * 8;
            const bf16* gb = BT + (size_t)(n0 + srow[p]) * K + kt + skc[p] * 8;
            gld16(ga, &lsA[cbase[p] * 8]);
            gld16(gb, &lsB[cbase[p] * 8]);
        }
        __syncthreads();

        short8 af[4][2], bfr[4][2];
#pragma unroll
        for (int i = 0; i < 4; i++) {
#pragma unroll
            for (int ks = 0; ks < 2; ks++) {
                int r = wm + i * 16 + ml;
                int kc = ks * 4 + q;
                af[i][ks] = *(const short8*)&lsA[(r * 8 + (kc ^ (r & 7))) * 8];
                int n = wn + i * 16 + ml;
                bfr[i][ks] = *(const short8*)&lsB[(n * 8 + (kc ^ (n & 7))) * 8];
            }
        }
#pragma unroll
        for (int ks = 0; ks < 2; ks++)
#pragma unroll
            for (int i = 0; i < 4; i++)
#pragma unroll
                for (int j = 0; j < 4; j++)
                    acc[i][j] = __builtin_amdgcn_mfma_f32_16x16x32_bf16(
                        af[i][ks], bfr[j][ks], acc[i][j], 0, 0, 0);
        __syncthreads();
    }

#pragma unroll
    for (int i = 0; i < 4; i++) {
#pragma unroll
        for (int j = 0; j < 4; j++) {
            int col = n0 + wn + j * 16 + ml;
            float bb = bias[col];
            float sc = (QKVQ && col < D_) ? 0.125f : 1.0f;
#pragma unroll
            for (int rg = 0; rg < 4; rg++) {
                int row = m0 + wm + i * 16 + q * 4 + rg;
                float v = acc[i][j][rg] + bb;
                if (ADDPOS) v += pos[(size_t)(row & (T_ - 1)) * N + col];
                if (RELU) v = fmaxf(v, 0.f);
                if (QKVQ) v *= sc;
                size_t idx = (size_t)row * N + col;
                if constexpr (sizeof(OutT) == 4) C[idx] = v;
                else C[idx] = (OutT)__float2bfloat16(v);
                if (DUAL) C2[idx] = __float2bfloat16(v);
            }
        }
    }
}

// ---------------------------------------------------------------------------
// MFMA attention. Block = (b, h, 64-query chunk); 4 waves x 16 q-rows.
// QKV: (NTOK, 3072) bf16, Q pre-scaled by 1/8. gbias: (B*T, T) bf16 additive.
// S strip (16x256) in registers; softmax via 16-lane shuffles; P through
// LDS (XOR-swizzled); V^T staged in LDS. Output fp32.
// ---------------------------------------------------------------------------
__global__ __launch_bounds__(256, 2)
void attn2_kernel(const bf16* __restrict__ QKV, const bf16* __restrict__ gbias,
                  const int* __restrict__ mask, float* __restrict__ O)
{
    __shared__ unsigned short lds[32768];       // [0,16384): V^T; [16384,32768): P
    const int tid = threadIdx.x;
    const int wv = tid >> 6, ln = tid & 63;
    const int ml = ln & 15, qq = ln >> 4;
    const int qc = blockIdx.x & 3;
    const int h  = (blockIdx.x >> 2) & 15;
    const int b  = blockIdx.x >> 6;
    const int tok0 = b * T_;

    const unsigned short* QKVu = (const unsigned short*)QKV;

    // ---- stage V^T (64 x 256, swizzled 16B chunks) ----
#pragma unroll
    for (int it = 0; it < 4; it++) {
        int k = (tid >> 2) + it * 64;
        int d0 = (tid & 3) * 16;
        const unsigned short* src = QKVu + (size_t)(tok0 + k) * 3072 + 2048 + h * 64 + d0;
        union { uint4 u[2]; unsigned short s[16]; } v;
        v.u[0] = *(const uint4*)src;
        v.u[1] = *(const uint4*)(src + 8);
#pragma unroll
        for (int e = 0; e < 16; e++) {
            int d = d0 + e;
            lds[d * 256 + (((k >> 3) ^ (d & 7)) << 3) + (k & 7)] = v.s[e];
        }
    }

    // ---- Q fragments (reused across all key tiles) ----
    const int q0 = qc * 64 + wv * 16;
    short8 qa[2];
#pragma unroll
    for (int ks = 0; ks < 2; ks++)
        qa[ks] = *(const short8*)(QKVu + (size_t)(tok0 + q0 + ml) * 3072 + h * 64 + ks * 32 + qq * 8);

    __syncthreads();

    // ---- S = Q K^T (16 j-tiles of 16 keys), K frags direct from global ----
    floatx4 sb[16] = {};
#pragma unroll
    for (int jt = 0; jt < 16; jt++) {
        const unsigned short* kr = QKVu + (size_t)(tok0 + jt * 16 + ml) * 3072 + 1024 + h * 64 + qq * 8;
        short8 kb0 = *(const short8*)kr;
        short8 kb1 = *(const short8*)(kr + 32);
        sb[jt] = __builtin_amdgcn_mfma_f32_16x16x32_bf16(qa[0], kb0, sb[jt], 0, 0, 0);
        sb[jt] = __builtin_amdgcn_mfma_f32_16x16x32_bf16(qa[1], kb1, sb[jt], 0, 0, 0);
    }

    // ---- add mask/graph bias ----
    const unsigned short* gb = (const unsigned short*)gbias + (size_t)(tok0 + q0) * T_;
#pragma unroll
    for (int jt = 0; jt < 16; jt++)
#pragma unroll
        for (int r = 0; r < 4; r++)
            sb[jt][r] += b2f(gb[(size_t)(qq * 4 + r) * T_ + jt * 16 + ml]);

    // ---- softmax (rows q0 + qq*4 + r) ----
    float mx[4];
#pragma unroll
    for (int r = 0; r < 4; r++) {
        float m = sb[0][r];
#pragma unroll
        for (int jt = 1; jt < 16; jt++) m = fmaxf(m, sb[jt][r]);
#pragma unroll
        for (int off = 1; off < 16; off <<= 1) m = fmaxf(m, __shfl_xor(m, off, 64));
        mx[r] = m;
    }
    float lsum[4] = {0.f, 0.f, 0.f, 0.f};
    unsigned short* Pw = lds + 16384 + wv * 4096;
#pragma unroll
    for (int jt = 0; jt < 16; jt++) {
#pragma unroll
        for (int r = 0; r < 4; r++) {
            float e = __expf(sb[jt][r] - mx[r]);
            lsum[r] += e;
            int row = qq * 4 + r;
            int k = jt * 16 + ml;
            Pw[row * 256 + (((k >> 3) ^ (row & 7)) << 3) + (k & 7)] = f2b(e);
        }
    }
#pragma unroll
    for (int r = 0; r < 4; r++)
#pragma unroll
        for (int off = 1; off < 16; off <<= 1) lsum[r] += __shfl_xor(lsum[r], off, 64);

    __syncthreads();

    // ---- O = P V (contraction over 256 keys, 8 MFMA steps) ----
    floatx4 oa[4] = {};
    const unsigned short* Pr = lds + 16384 + wv * 4096;
#pragma unroll
    for (int ks = 0; ks < 8; ks++) {
        short8 pa = *(const short8*)&Pr[ml * 256 + (((ks * 4 + qq) ^ (ml & 7)) << 3)];
#pragma unroll
        for (int jd = 0; jd < 4; jd++) {
            int n = jd * 16 + ml;
            short8 vb = *(const short8*)&lds[n * 256 + (((ks * 4 + qq) ^ (n & 7)) << 3)];
            oa[jd] = __builtin_amdgcn_mfma_f32_16x16x32_bf16(pa, vb, oa[jd], 0, 0, 0);
        }
    }

    // ---- epilogue: scale by 1/l and query mask ----
    float fin[4];
#pragma unroll
    for (int r = 0; r < 4; r++) {
        int row = q0 + qq * 4 + r;
        fin[r] = (float)mask[tok0 + row] / lsum[r];
    }
#pragma unroll
    for (int jd = 0; jd < 4; jd++)
#pragma unroll
        for (int r = 0; r < 4; r++) {
            int row = q0 + qq * 4 + r;
            O[(size_t)(tok0 + row) * D_ + h * 64 + jd * 16 + ml] = oa[jd][r] * fin[r];
        }
}

// ---------------------------------------------------------------------------
// Residual add + LayerNorm (fp32) + bf16 copy
// ---------------------------------------------------------------------------
__global__ __launch_bounds__(256)
void add_ln_kernel(const float* __restrict__ Xin, const float* __restrict__ Yin,
                   const float* __restrict__ g, const float* __restrict__ beta,
                   float* __restrict__ Out, bf16* __restrict__ Outb)
{
    const int row = blockIdx.x;
    const int tid = threadIdx.x;
    const float4 a = ((const float4*)(Xin + (size_t)row * D_))[tid];
    const float4 b = ((const float4*)(Yin + (size_t)row * D_))[tid];
    float v0 = a.x + b.x, v1 = a.y + b.y, v2 = a.z + b.z, v3 = a.w + b.w;

    __shared__ float red[8];
    float lsum = v0 + v1 + v2 + v3;
#pragma unroll
    for (int off = 32; off > 0; off >>= 1) lsum += __shfl_xor(lsum, off, 64);
    int wave = tid >> 6;
    if ((tid & 63) == 0) red[wave] = lsum;
    __syncthreads();
    float mean = (red[0] + red[1] + red[2] + red[3]) * (1.f / (float)D_);

    float d0 = v0 - mean, d1 = v1 - mean, d2 = v2 - mean, d3 = v3 - mean;
    float ls2 = d0 * d0 + d1 * d1 + d2 * d2 + d3 * d3;
#pragma unroll
    for (int off = 32; off > 0; off >>= 1) ls2 += __shfl_xor(ls2, off, 64);
    if ((tid & 63) == 0) red[4 + wave] = ls2;
    __syncthreads();
    float var = (red[4] + red[5] + red[6] + red[7]) * (1.f / (float)D_);
    float inv = 1.f / sqrtf(var + 1e-8f);

    int col = tid * 4;
    float4 gv = *(const float4*)(g + col);
    float4 bv = *(const float4*)(beta + col);
    float4 o;
    o.x = d0 * inv * gv.x + bv.x;
    o.y = d1 * inv * gv.y + bv.y;
    o.z = d2 * inv * gv.z + bv.z;
    o.w = d3 * inv * gv.w + bv.w;
    ((float4*)(Out + (size_t)row * D_))[tid] = o;

    union { unsigned short u[4]; uint2 v; } pk;
    pk.u[0] = f2b(o.x); pk.u[1] = f2b(o.y); pk.u[2] = f2b(o.z); pk.u[3] = f2b(o.w);
    *(uint2*)&Outb[(size_t)row * D_ + col] = pk.v;
}

// ---------------------------------------------------------------------------
extern "C" void kernel_launch(void* const* d_in, const int* in_sizes, int n_in,
                              void* d_out, int out_size, void* d_ws, size_t ws_size,
                              hipStream_t stream)
{
    const int*   syb_ipt   = (const int*)d_in[0];
    const int*   syb_mask  = (const int*)d_in[1];
    const int*   syb_graph = (const int*)d_in[2];
    const float* emb       = (const float*)d_in[3];
    const float* mlp_w1    = (const float*)d_in[4];
    const float* mlp_b1    = (const float*)d_in[5];
    const float* mlp_w2    = (const float*)d_in[6];
    const float* mlp_b2    = (const float*)d_in[7];
    const float* pos       = (const float*)d_in[8];
    const float* wq        = (const float*)d_in[9];
    const float* bq        = (const float*)d_in[10];
    const float* wk        = (const float*)d_in[11];
    const float* bk        = (const float*)d_in[12];
    const float* wv        = (const float*)d_in[13];
    const float* bv        = (const float*)d_in[14];
    const float* ln1g      = (const float*)d_in[15];
    const float* ln1b      = (const float*)d_in[16];
    const float* ffw1      = (const float*)d_in[17];
    const float* ffb1      = (const float*)d_in[18];
    const float* ffw2      = (const float*)d_in[19];
    const float* ffb2      = (const float*)d_in[20];
    const float* ln2g      = (const float*)d_in[21];
    const float* ln2b      = (const float*)d_in[22];

    char* p = (char*)d_ws;
    auto alloc = [&](size_t bytes) { char* r = p; p += (bytes + 255) & ~(size_t)255; return r; };
    float* X    = (float*)alloc((size_t)NTOK * D_ * 4);
    float* Rb   = (float*)alloc((size_t)NTOK * D_ * 4);
    bf16*  Xb   = (bf16*)alloc((size_t)NTOK * D_ * 2);
    bf16*  EMBb = (bf16*)alloc((size_t)NTOK * GDP_ * 2);
    bf16*  Hb   = (bf16*)alloc((size_t)NTOK * FFH_ * 2);
    bf16*  QKVb = (bf16*)alloc((size_t)NTOK * 3072 * 2);
    bf16*  qkvT = (bf16*)alloc((size_t)NB_ * 3072 * D_ * 2);
    bf16*  f1T  = (bf16*)alloc((size_t)NB_ * D_ * FFH_ * 2);
    bf16*  f2T  = (bf16*)alloc((size_t)NB_ * D_ * FFH_ * 2);
    bf16*  m1T  = (bf16*)alloc((size_t)MLPH_ * GDP_ * 2);
    bf16*  m2T  = (bf16*)alloc((size_t)D_ * MLPH_ * 2);
    float* bqkv = (float*)alloc((size_t)NB_ * 3072 * 4);
    bf16*  gB   = (bf16*)alloc((size_t)NTOK * T_ * 2);

    // ---- prep: weights, biases, graph bias, embedding ----
    convT_kernel<<<dim3(D_ / 32, D_ / 32, NB_), 256, 0, stream>>>(
        wq, qkvT + 0, D_, D_, D_, (size_t)D_ * D_, (size_t)3072 * D_);
    convT_kernel<<<dim3(D_ / 32, D_ / 32, NB_), 256, 0, stream>>>(
        wk, qkvT + (size_t)1024 * D_, D_, D_, D_, (size_t)D_ * D_, (size_t)3072 * D_);
    convT_kernel<<<dim3(D_ / 32, D_ / 32, NB_), 256, 0, stream>>>(
        wv, qkvT + (size_t)2048 * D_, D_, D_, D_, (size_t)D_ * D_, (size_t)3072 * D_);
    convT_kernel<<<dim3(FFH_ / 32, D_ / 32, NB_), 256, 0, stream>>>(
        ffw1, f1T, D_, FFH_, D_, (size_t)D_ * FFH_, (size_t)D_ * FFH_);
    convT_kernel<<<dim3(D_ / 32, FFH_ / 32, NB_), 256, 0, stream>>>(
        ffw2, f2T, FFH_, D_, FFH_, (size_t)D_ * FFH_, (size_t)D_ * FFH_);
    convT_kernel<<<dim3(MLPH_ / 32, GDP_ / 32, 1), 256, 0, stream>>>(
        mlp_w1, m1T, GD_, MLPH_, GDP_, 0, 0);
    convT_kernel<<<dim3(D_ / 32, MLPH_ / 32, 1), 256, 0, stream>>>(
        mlp_w2, m2T, MLPH_, D_, MLPH_, 0, 0);
    bcat_kernel<<<dim3(NB_, 12), 256, 0, stream>>>(bq, bk, bv, bqkv);
    gbias_kernel<<<NTOK, 256, 0, stream>>>(syb_mask, syb_graph, gB);
    gather_kernel<<<NTOK, 256, 0, stream>>>(syb_ipt, emb, EMBb);

    // ---- MLP ----
    mm_bf16<true, false, false, false, bf16><<<dim3(MLPH_ / 128, NTOK / 128), 256, 0, stream>>>(
        EMBb, m1T, mlp_b1, nullptr, Hb, nullptr, NTOK, MLPH_, GDP_);
    mm_bf16<false, true, true, false, float><<<dim3(D_ / 128, NTOK / 128), 256, 0, stream>>>(
        Hb, m2T, mlp_b2, pos, X, Xb, NTOK, D_, MLPH_);

    for (int i = 0; i < NB_; i++) {
        // fused QKV projection (relu, Q scaled by 1/8)
        mm_bf16<true, false, false, true, bf16><<<dim3(3072 / 128, NTOK / 128), 256, 0, stream>>>(
            Xb, qkvT + (size_t)i * 3072 * D_, bqkv + (size_t)i * 3072, nullptr,
            QKVb, nullptr, NTOK, 3072, D_);

        attn2_kernel<<<B_ * H_ * 4, 256, 0, stream>>>(QKVb, gB, syb_mask, Rb);

        add_ln_kernel<<<NTOK, 256, 0, stream>>>(
            X, Rb, ln1g + (size_t)i * D_, ln1b + (size_t)i * D_, X, Xb);

        mm_bf16<true, false, false, false, bf16><<<dim3(FFH_ / 128, NTOK / 128), 256, 0, stream>>>(
            Xb, f1T + (size_t)i * D_ * FFH_, ffb1 + (size_t)i * FFH_, nullptr, Hb, nullptr, NTOK, FFH_, D_);
        mm_bf16<false, false, false, false, float><<<dim3(D_ / 128, NTOK / 128), 256, 0, stream>>>(
            Hb, f2T + (size_t)i * D_ * FFH_, ffb2 + (size_t)i * D_, nullptr, Rb, nullptr, NTOK, D_, FFH_);

        float* out_ptr = (i == NB_ - 1) ? (float*)d_out : X;
        add_ln_kernel<<<NTOK, 256, 0, stream>>>(
            X, Rb, ln2g + (size_t)i * D_, ln2b + (size_t)i * D_, out_ptr, Xb);
    }
}